// Round 10
// baseline (33.040 us; speedup 1.0000x reference)
//
#include <hip/hip_runtime.h>

// Focal loss: out[0]=loss_pos, out[1]=loss_neg, out[2]=count_pos, out[3]=count_neg
// ALPHA=2, FPN_POS_FACTOR=(2,1), FPN_NEG_FACTOR=(2,1), ANCHOR_POS_FACTOR={1,1}
// logit0: [8,2,64,128,128] f32 (16,777,216), logit1: [8,2,32,64,64] f32 (2,097,152)
//
// R9 post-mortem: sched_barrier(0) is defeated at IR level (loads sink past
// intrinsic calls before the machine scheduler runs) -> VGPR fell to 20.
// R10: pin the 8 staged loads with an empty asm volatile "+v" tie on native
// ext_vector values -- codegen MUST materialize all 8 float4s in VGPRs at
// that point, so all 8 global_load_dwordx4 issue before any compute.

#define LOG2E 1.44269504088896340736f
#define LN2   0.69314718055994530942f

typedef float f32x4 __attribute__((ext_vector_type(4)));

__device__ __forceinline__ float exp2_hw(float x) { return __builtin_amdgcn_exp2f(x); }
__device__ __forceinline__ float log2_hw(float x) { return __builtin_amdgcn_logf(x); }  // v_log_f32 = log2
__device__ __forceinline__ float rcp_hw(float x)  { return __builtin_amdgcn_rcpf(x); }

// w = sigmoid(x)^2*[g==-1]; loss += softplus(x)*w; count += w
__device__ __forceinline__ void neg_elem(float x, float g, float& lsum, float& csum) {
    float z  = fmaxf(x * LOG2E, -43.0f);    // clamp: below this weight < 1e-26
    float t  = exp2_hw(-z);                 // e^{-x}
    float u  = 1.0f + t;
    float r  = rcp_hw(u);                   // sigmoid(x)
    float w  = (g == -1.0f) ? r * r : 0.0f; // prob^2 * negmask
    float sp = LN2 * (z + log2_hw(u));      // softplus(x)
    csum += w;
    lsum += sp * w;
}

__device__ __forceinline__ void neg_quad(f32x4 x4, f32x4 g4, float& lsum, float& csum) {
    neg_elem(x4.x, g4.x, lsum, csum);
    neg_elem(x4.y, g4.y, lsum, csum);
    neg_elem(x4.z, g4.z, lsum, csum);
    neg_elem(x4.w, g4.w, lsum, csum);
}

// Each 256-thread block covers 1024 float4-quads (4096 floats) of one level.
// Blocks [0,nblk0) -> L0, rest -> L1. Partials to ws[blk] (no atomics).
__global__ void __launch_bounds__(256, 2) neg_loss_kernel(
        const f32x4* __restrict__ x0, const f32x4* __restrict__ g0,
        const f32x4* __restrict__ x1, const f32x4* __restrict__ g1,
        int nblk0, float2* __restrict__ ws) {
    const int lane = threadIdx.x & 63;
    const int wav  = threadIdx.x >> 6;
    const f32x4* __restrict__ xp;
    const f32x4* __restrict__ gp;
    float f;
    int idx;
    if ((int)blockIdx.x < nblk0) {
        xp = x0; gp = g0; f = 2.0f;
        idx = blockIdx.x * 1024 + wav * 256 + lane;
    } else {
        xp = x1; gp = g1; f = 1.0f;
        idx = (blockIdx.x - nblk0) * 1024 + wav * 256 + lane;
    }
    // 8 independent 16B loads. The asm tie forces all 8 values to be
    // materialized in VGPRs here -> no load can sink into the compute.
    f32x4 xa = xp[idx      ];
    f32x4 xb = xp[idx +  64];
    f32x4 xc = xp[idx + 128];
    f32x4 xd = xp[idx + 192];
    f32x4 ga = gp[idx      ];
    f32x4 gb = gp[idx +  64];
    f32x4 gc = gp[idx + 128];
    f32x4 gd = gp[idx + 192];
    asm volatile("" : "+v"(xa), "+v"(xb), "+v"(xc), "+v"(xd),
                      "+v"(ga), "+v"(gb), "+v"(gc), "+v"(gd));

    float lsum = 0.0f, csum = 0.0f;
    neg_quad(xa, ga, lsum, csum);
    neg_quad(xb, gb, lsum, csum);
    neg_quad(xc, gc, lsum, csum);
    neg_quad(xd, gd, lsum, csum);
    lsum *= f;  // FPN_NEG_FACTOR baked per block

    #pragma unroll
    for (int off = 32; off > 0; off >>= 1) {
        lsum += __shfl_down(lsum, off);
        csum += __shfl_down(csum, off);
    }
    __shared__ float sl[4], sc[4];
    if (lane == 0) { sl[wav] = lsum; sc[wav] = csum; }
    __syncthreads();
    if (threadIdx.x == 0) {
        ws[blockIdx.x] = make_float2(sl[0] + sl[1] + sl[2] + sl[3],
                                     sc[0] + sc[1] + sc[2] + sc[3]);
    }
}

// One block, 1024 threads: positive (gathered) term + reduce ws partials.
__global__ void __launch_bounds__(1024) finalize_kernel(
        const float* __restrict__ logit0, const int* __restrict__ coord0,
        const float* __restrict__ logit1, const int* __restrict__ coord1,
        const float2* __restrict__ ws, int nblk,
        float* __restrict__ out) {
    const int j = threadIdx.x;
    float lp = 0.0f, cp = 0.0f;
    {
        const int level = (j >= 512);
        const int jj = level ? (j - 512) : j;
        const int b = jj >> 6;  // P = 64
        const int* cptr = (level ? coord1 : coord0) + jj * 4;
        int c0 = cptr[0], c1 = cptr[1], c2 = cptr[2], c3 = cptr[3];
        const bool v = (c0 > -1);
        const float valid = v ? 1.0f : 0.0f;
        if (!v) { c0 = 0; c1 = 0; c2 = 0; c3 = 0; }
        long off;
        const float* lg;
        float posf;
        if (!level) {
            off = ((((long)b * 2 + c0) * 64 + c1) * 128 + c2) * 128 + c3;  // [8][2][64][128][128]
            lg = logit0; posf = 2.0f;
        } else {
            off = ((((long)b * 2 + c0) * 32 + c1) * 64 + c2) * 64 + c3;   // [8][2][32][64][64]
            lg = logit1; posf = 1.0f;
        }
        const float x = lg[off];
        // w = (1-sigmoid(x))^2 * valid;  -log_sigmoid(x) = softplus(-x)
        float z  = fmaxf(-x * LOG2E, -43.0f);
        float t  = exp2_hw(-z);                 // e^{x}
        float u  = 1.0f + t;
        float r  = rcp_hw(u);                   // 1 - sigmoid(x)
        float w  = r * r * valid;
        float sp = LN2 * (z + log2_hw(u));      // softplus(-x)
        lp = sp * w * posf;                     // w2 = ANCHOR_POS_FACTOR = 1
        cp = w;
    }
    float ln = 0.0f, cn = 0.0f;
    for (int i = j; i < nblk; i += 1024) {
        float2 p = ws[i];
        ln += p.x;
        cn += p.y;
    }
    #pragma unroll
    for (int off = 32; off > 0; off >>= 1) {
        lp += __shfl_down(lp, off);
        cp += __shfl_down(cp, off);
        ln += __shfl_down(ln, off);
        cn += __shfl_down(cn, off);
    }
    __shared__ float sl[16], sc[16], sln[16], scn[16];
    int wav = threadIdx.x >> 6, lane = threadIdx.x & 63;
    if (lane == 0) { sl[wav] = lp; sc[wav] = cp; sln[wav] = ln; scn[wav] = cn; }
    __syncthreads();
    if (threadIdx.x == 0) {
        float tl = 0.0f, tc = 0.0f, tln = 0.0f, tcn = 0.0f;
        #pragma unroll
        for (int i = 0; i < 16; ++i) { tl += sl[i]; tc += sc[i]; tln += sln[i]; tcn += scn[i]; }
        out[0] = tl;
        out[1] = tln;
        out[2] = tc;
        out[3] = tcn;
    }
}

extern "C" void kernel_launch(void* const* d_in, const int* in_sizes, int n_in,
                              void* d_out, int out_size, void* d_ws, size_t ws_size,
                              hipStream_t stream) {
    const float* logit0 = (const float*)d_in[0];
    const float* logit1 = (const float*)d_in[1];
    const float* gt0    = (const float*)d_in[2];
    const float* gt1    = (const float*)d_in[3];
    const int*   coord0 = (const int*)d_in[4];
    const int*   coord1 = (const int*)d_in[5];
    float* out = (float*)d_out;
    float2* ws = (float2*)d_ws;

    const int n0 = in_sizes[0];  // 16,777,216 = 4096 blocks * 4096 floats
    const int n1 = in_sizes[1];  //  2,097,152 =  512 blocks * 4096 floats
    const int nblk0 = n0 >> 12;
    const int nblk1 = n1 >> 12;
    const int nblk = nblk0 + nblk1;

    neg_loss_kernel<<<nblk, 256, 0, stream>>>(
        (const f32x4*)logit0, (const f32x4*)gt0,
        (const f32x4*)logit1, (const f32x4*)gt1, nblk0, ws);
    finalize_kernel<<<1, 1024, 0, stream>>>(
        logit0, coord0, logit1, coord1, ws, nblk, out);
}

// Round 11
// 30.709 us; speedup vs baseline: 1.0759x; 1.0759x over previous
//
#include <hip/hip_runtime.h>

// Focal loss: out[0]=loss_pos, out[1]=loss_neg, out[2]=count_pos, out[3]=count_neg
// ALPHA=2, FPN_POS_FACTOR=(2,1), FPN_NEG_FACTOR=(2,1), ANCHOR_POS_FACTOR={1,1}
// logit0: [8,2,64,128,128] f32 (16,777,216), logit1: [8,2,32,64,64] f32 (2,097,152)
//
// R10 post-mortem: VGPR 20/28/48 x {serial, prefetch, sched_barrier, asm-tie}
// all land 32-38us -> per-wave MLP exonerated; neg kernel is at the memory-
// system plateau (~5 TB/s HBM+L3 mix). R11: shave the serial tail. The pos
// gather is independent of ws -> fold it into the first kernel as block 0
// (runs concurrently with neg blocks, writes out[0]/out[2] directly).
// finalize becomes a bare 36KB ws-reduce (launch-latency bound).

#define LOG2E 1.44269504088896340736f
#define LN2   0.69314718055994530942f

__device__ __forceinline__ float exp2_hw(float x) { return __builtin_amdgcn_exp2f(x); }
__device__ __forceinline__ float log2_hw(float x) { return __builtin_amdgcn_logf(x); }  // v_log_f32 = log2
__device__ __forceinline__ float rcp_hw(float x)  { return __builtin_amdgcn_rcpf(x); }

// w = sigmoid(x)^2*[g==-1]; loss += softplus(x)*w; count += w
__device__ __forceinline__ void neg_elem(float x, float g, float& lsum, float& csum) {
    float z  = fmaxf(x * LOG2E, -43.0f);    // clamp: below this weight < 1e-26
    float t  = exp2_hw(-z);                 // e^{-x}
    float u  = 1.0f + t;
    float r  = rcp_hw(u);                   // sigmoid(x)
    float w  = (g == -1.0f) ? r * r : 0.0f; // prob^2 * negmask
    float sp = LN2 * (z + log2_hw(u));      // softplus(x)
    csum += w;
    lsum += sp * w;
}

__device__ __forceinline__ void neg_quad(float4 x4, float4 g4, float& lsum, float& csum) {
    neg_elem(x4.x, g4.x, lsum, csum);
    neg_elem(x4.y, g4.y, lsum, csum);
    neg_elem(x4.z, g4.z, lsum, csum);
    neg_elem(x4.w, g4.w, lsum, csum);
}

// Block 0: pos gather (writes out[0], out[2] directly -- no ws dependency).
// Blocks 1..nblk: neg work, 1024 float4-quads each; partial to ws[bid-1].
__global__ void __launch_bounds__(256, 2) main_kernel(
        const float4* __restrict__ x0, const float4* __restrict__ g0,
        const float4* __restrict__ x1, const float4* __restrict__ g1,
        int nblk0,
        const float* __restrict__ logit0, const int* __restrict__ coord0,
        const float* __restrict__ logit1, const int* __restrict__ coord1,
        float2* __restrict__ ws, float* __restrict__ out) {
    const int tid  = threadIdx.x;
    const int lane = tid & 63;
    const int wav  = tid >> 6;
    __shared__ float sa[4], sb[4];

    if (blockIdx.x == 0) {
        // ---- positive (gathered) term: 1024 items, 4 per thread ----
        float lp = 0.0f, cp = 0.0f;
        #pragma unroll
        for (int k = 0; k < 4; ++k) {
            const int item  = tid + k * 256;
            const int level = (item >= 512);
            const int jj    = level ? (item - 512) : item;
            const int b     = jj >> 6;  // P = 64
            const int* cptr = (level ? coord1 : coord0) + jj * 4;
            int c0 = cptr[0], c1 = cptr[1], c2 = cptr[2], c3 = cptr[3];
            const bool v = (c0 > -1);
            const float valid = v ? 1.0f : 0.0f;
            if (!v) { c0 = 0; c1 = 0; c2 = 0; c3 = 0; }
            long off; const float* lg; float posf;
            if (!level) {
                off = ((((long)b * 2 + c0) * 64 + c1) * 128 + c2) * 128 + c3;  // [8][2][64][128][128]
                lg = logit0; posf = 2.0f;
            } else {
                off = ((((long)b * 2 + c0) * 32 + c1) * 64 + c2) * 64 + c3;    // [8][2][32][64][64]
                lg = logit1; posf = 1.0f;
            }
            const float x = lg[off];
            // w = (1-sigmoid(x))^2 * valid;  -log_sigmoid(x) = softplus(-x)
            float z  = fmaxf(-x * LOG2E, -43.0f);
            float t  = exp2_hw(-z);
            float u  = 1.0f + t;
            float r  = rcp_hw(u);               // 1 - sigmoid(x)
            float w  = r * r * valid;
            float sp = LN2 * (z + log2_hw(u));  // softplus(-x)
            lp += sp * w * posf;                // ANCHOR_POS_FACTOR = 1
            cp += w;
        }
        #pragma unroll
        for (int off = 32; off > 0; off >>= 1) {
            lp += __shfl_down(lp, off);
            cp += __shfl_down(cp, off);
        }
        if (lane == 0) { sa[wav] = lp; sb[wav] = cp; }
        __syncthreads();
        if (tid == 0) {
            out[0] = sa[0] + sa[1] + sa[2] + sa[3];
            out[2] = sb[0] + sb[1] + sb[2] + sb[3];
        }
        return;
    }

    // ---- negative term ----
    const int bid = blockIdx.x - 1;
    const float4* __restrict__ xp;
    const float4* __restrict__ gp;
    float f;
    int idx;
    if (bid < nblk0) {
        xp = x0; gp = g0; f = 2.0f;
        idx = bid * 1024 + wav * 256 + lane;
    } else {
        xp = x1; gp = g1; f = 1.0f;
        idx = (bid - nblk0) * 1024 + wav * 256 + lane;
    }
    float4 xa = xp[idx      ];
    float4 ga = gp[idx      ];
    float4 xb = xp[idx +  64];
    float4 gb = gp[idx +  64];
    float4 xc = xp[idx + 128];
    float4 gc = gp[idx + 128];
    float4 xd = xp[idx + 192];
    float4 gd = gp[idx + 192];

    float lsum = 0.0f, csum = 0.0f;
    neg_quad(xa, ga, lsum, csum);
    neg_quad(xb, gb, lsum, csum);
    neg_quad(xc, gc, lsum, csum);
    neg_quad(xd, gd, lsum, csum);
    lsum *= f;  // FPN_NEG_FACTOR baked per block

    #pragma unroll
    for (int off = 32; off > 0; off >>= 1) {
        lsum += __shfl_down(lsum, off);
        csum += __shfl_down(csum, off);
    }
    if (lane == 0) { sa[wav] = lsum; sb[wav] = csum; }
    __syncthreads();
    if (tid == 0) {
        ws[bid] = make_float2(sa[0] + sa[1] + sa[2] + sa[3],
                              sb[0] + sb[1] + sb[2] + sb[3]);
    }
}

// 256 threads, one block: reduce nblk float2 partials -> out[1], out[3].
// ws read as float4 (two partials per load): 2304 float4s, 9 per thread.
__global__ void __launch_bounds__(256) reduce_ws_kernel(
        const float4* __restrict__ ws4, int nq,
        float* __restrict__ out) {
    const int tid = threadIdx.x;
    float ln = 0.0f, cn = 0.0f;
    for (int i = tid; i < nq; i += 256) {
        float4 v = ws4[i];
        ln += v.x + v.z;
        cn += v.y + v.w;
    }
    #pragma unroll
    for (int off = 32; off > 0; off >>= 1) {
        ln += __shfl_down(ln, off);
        cn += __shfl_down(cn, off);
    }
    __shared__ float sl[4], sc[4];
    const int wav = tid >> 6, lane = tid & 63;
    if (lane == 0) { sl[wav] = ln; sc[wav] = cn; }
    __syncthreads();
    if (tid == 0) {
        out[1] = sl[0] + sl[1] + sl[2] + sl[3];
        out[3] = sc[0] + sc[1] + sc[2] + sc[3];
    }
}

extern "C" void kernel_launch(void* const* d_in, const int* in_sizes, int n_in,
                              void* d_out, int out_size, void* d_ws, size_t ws_size,
                              hipStream_t stream) {
    const float* logit0 = (const float*)d_in[0];
    const float* logit1 = (const float*)d_in[1];
    const float* gt0    = (const float*)d_in[2];
    const float* gt1    = (const float*)d_in[3];
    const int*   coord0 = (const int*)d_in[4];
    const int*   coord1 = (const int*)d_in[5];
    float* out = (float*)d_out;
    float2* ws = (float2*)d_ws;

    const int n0 = in_sizes[0];  // 16,777,216 = 4096 blocks * 4096 floats
    const int n1 = in_sizes[1];  //  2,097,152 =  512 blocks * 4096 floats
    const int nblk0 = n0 >> 12;
    const int nblk1 = n1 >> 12;
    const int nblk = nblk0 + nblk1;          // 4608 neg blocks

    main_kernel<<<nblk + 1, 256, 0, stream>>>(
        (const float4*)logit0, (const float4*)gt0,
        (const float4*)logit1, (const float4*)gt1, nblk0,
        logit0, coord0, logit1, coord1, ws, out);
    reduce_ws_kernel<<<1, 256, 0, stream>>>(
        (const float4*)ws, nblk / 2, out);
}